// Round 4
// baseline (177.042 us; speedup 1.0000x reference)
//
#include <hip/hip_runtime.h>
#include <hip/hip_bf16.h>
#include <cstdint>

#define BATCH   32
#define NVARS   16
#define SAMPLES 4096
#define EDIM    128
#define NTOK    1016          // (4096-32)/4
#define KDIM    4096

typedef __bf16 bf8_t __attribute__((ext_vector_type(8)));
typedef float  f4_t  __attribute__((ext_vector_type(4)));

__device__ __forceinline__ void gload_lds16(const void* g, void* l) {
  __builtin_amdgcn_global_load_lds(
      (const __attribute__((address_space(1))) unsigned int*)g,
      (__attribute__((address_space(3))) unsigned int*)l, 16, 0, 0);
}

// ---------------------------------------------------------------------------
// Stage 1: enc_p[b][phase][eblk][u][32] = floor(x@Ws + bs), bf16 (ints exact).
// phase=s&3, u=s>>2, eblk=d>>5. Chunk swizzle baked in: phys=(c+(u>>1))&3.
// This makes every GEMM A-tile an 8 KB CONTIGUOUS block (kills VMEM scatter).
// ---------------------------------------------------------------------------
__global__ __launch_bounds__(256) void encode_kernel(
    const float* __restrict__ x, const float* __restrict__ Ws,
    const float* __restrict__ bs, __hip_bfloat16* __restrict__ enc)
{
  __shared__ float xs[NVARS][256];
  int tid = threadIdx.x;
  int b   = blockIdx.x >> 4;
  int s0  = (blockIdx.x & 15) << 8;

  const float* xb = x + (size_t)b * NVARS * SAMPLES + s0;
  {
    int col = (tid & 63) << 2;
    int v0  = tid >> 6;
#pragma unroll
    for (int j = 0; j < 4; ++j) {
      int v = v0 + j * 4;
      float4 t = *(const float4*)(xb + (size_t)v * SAMPLES + col);
      *(float4*)&xs[v][col] = t;
    }
  }

  int d0 = (tid & 31) * 4;
  int sl = tid >> 5;
  float w[NVARS][4];
#pragma unroll
  for (int v = 0; v < NVARS; ++v) {
    float4 t = *(const float4*)&Ws[v * EDIM + d0];
    w[v][0] = t.x; w[v][1] = t.y; w[v][2] = t.z; w[v][3] = t.w;
  }
  float4 bias = *(const float4*)&bs[d0];

  __syncthreads();

  int eblk = d0 >> 5;
  int c    = (d0 >> 3) & 3;
  int half = (d0 >> 2) & 1;
#pragma unroll 4
  for (int pass = 0; pass < 32; ++pass) {
    int s = s0 + pass * 8 + sl;
    int ls = pass * 8 + sl;
    float a0 = bias.x, a1 = bias.y, a2 = bias.z, a3 = bias.w;
#pragma unroll
    for (int v = 0; v < NVARS; ++v) {
      float xv = xs[v][ls];
      a0 += xv * w[v][0]; a1 += xv * w[v][1];
      a2 += xv * w[v][2]; a3 += xv * w[v][3];
    }
    union { unsigned short u[4]; uint2 qq; } pk;
    pk.u[0] = (unsigned short)(__float_as_uint(floorf(a0)) >> 16);
    pk.u[1] = (unsigned short)(__float_as_uint(floorf(a1)) >> 16);
    pk.u[2] = (unsigned short)(__float_as_uint(floorf(a2)) >> 16);
    pk.u[3] = (unsigned short)(__float_as_uint(floorf(a3)) >> 16);
    int u  = s >> 2, phase = s & 3;
    int p  = (c + (u >> 1)) & 3;
    size_t off = ((((size_t)b * 4 + phase) * 4 + eblk) << 15)
               + (size_t)u * 32 + p * 8 + half * 4;
    *(uint2*)(enc + off) = pk.qq;
  }
}

// ---------------------------------------------------------------------------
// W_patch [4096][128] fp32 -> Wt_p[kb(128)][n(128)][32] bf16, swizzled
// phys=(c+(n>>1))&3.  kb -> k rows (kb>>2)*128 + (kb&3)*32 .. +32.
// B-tiles become 8 KB contiguous.
// ---------------------------------------------------------------------------
__global__ __launch_bounds__(256) void twp_kernel(
    const float* __restrict__ Wp, __hip_bfloat16* __restrict__ Wt)
{
  __shared__ float ls[32][129];
  int kb    = blockIdx.x;
  int kbase = (kb >> 2) * 128 + (kb & 3) * 32;
#pragma unroll
  for (int r = 0; r < 16; ++r) {
    int idx = threadIdx.x + r * 256;
    ls[idx >> 7][idx & 127] = Wp[(size_t)(kbase + (idx >> 7)) * EDIM + (idx & 127)];
  }
  __syncthreads();
#pragma unroll
  for (int i = 0; i < 2; ++i) {
    int q = threadIdx.x * 2 + i;       // 0..511
    int n = q >> 2, c = q & 3;
    int p = (c + (n >> 1)) & 3;
    union { unsigned short u[8]; uint4 v; } pk;
#pragma unroll
    for (int j = 0; j < 8; ++j) {
      __hip_bfloat16 h = __float2bfloat16(ls[c * 8 + j][n]);
      pk.u[j] = *(unsigned short*)&h;
    }
    *(uint4*)(Wt + ((size_t)kb << 12) + n * 32 + p * 8) = pk.v;
  }
}

// ---------------------------------------------------------------------------
// Stage 2 GEMM: M=32512 N=128 K=4096. BM=BN=128 BK=32, 4 waves, 64x64 wave
// tiles (4x4 mfma 16x16x32). Ring-4 LDS (64 KB), prefetch distance 3,
// s_waitcnt vmcnt(8) gates. ALL staging loads are 1 KB contiguous
// (lane i -> base+16i), matching global_load_lds LDS semantics.
// ---------------------------------------------------------------------------
__global__ __launch_bounds__(256) void gemm_kernel(
    const __hip_bfloat16* __restrict__ enc,
    const __hip_bfloat16* __restrict__ Wt,
    const float* __restrict__ bp,
    float* __restrict__ out)
{
  __shared__ __align__(16) __hip_bfloat16 sA[4][128 * 32];  // 32 KB
  __shared__ __align__(16) __hip_bfloat16 sB[4][128 * 32];  // 32 KB

  int tid  = threadIdx.x;
  int lane = tid & 63;
  int wv   = tid >> 6;
  int b    = blockIdx.x >> 3;
  int t0   = (blockIdx.x & 7) << 7;
  int wm   = (wv >> 1) << 6;          // 0/64
  int wn   = (wv & 1) << 6;           // 0/64
  int quad = lane >> 4;
  int l15  = lane & 15;

  f4_t acc[4][4];
  f4_t zero = {0.f, 0.f, 0.f, 0.f};
#pragma unroll
  for (int i = 0; i < 4; ++i)
#pragma unroll
    for (int j = 0; j < 4; ++j) acc[i][j] = zero;

  auto stage = [&](int kb, int slot) {
    int phase = (kb >> 2) & 3, eblk = kb & 3;
    int u0 = t0 + (kb >> 4);
    const __hip_bfloat16* ga = enc
        + (((((size_t)b * 4 + phase) * 4 + eblk)) << 15)
        + (size_t)(u0 + wv * 32) * 32 + lane * 8;
    gload_lds16(ga,       &sA[slot][(wv * 32) * 32]);
    gload_lds16(ga + 512, &sA[slot][(wv * 32 + 16) * 32]);
    const __hip_bfloat16* gb = Wt + ((size_t)kb << 12) + (wv * 32) * 32 + lane * 8;
    gload_lds16(gb,       &sB[slot][(wv * 32) * 32]);
    gload_lds16(gb + 512, &sB[slot][(wv * 32 + 16) * 32]);
  };

  int swzB = (quad + (l15 >> 1)) & 3;
  auto compute = [&](int slot, int kb) {
    int swzA = (quad + (((kb >> 4) + l15) >> 1)) & 3;
    const bf8_t* pA = (const bf8_t*)sA[slot];
    const bf8_t* pB = (const bf8_t*)sB[slot];
    bf8_t af[4], bfr[4];
#pragma unroll
    for (int i = 0; i < 4; ++i) af[i]  = pA[(wm + i * 16 + l15) * 4 + swzA];
#pragma unroll
    for (int j = 0; j < 4; ++j) bfr[j] = pB[(wn + j * 16 + l15) * 4 + swzB];
#pragma unroll
    for (int mi = 0; mi < 4; ++mi)
#pragma unroll
      for (int ni = 0; ni < 4; ++ni)
        acc[mi][ni] = __builtin_amdgcn_mfma_f32_16x16x32_bf16(
            af[mi], bfr[ni], acc[mi][ni], 0, 0, 0);
  };

  stage(0, 0); stage(1, 1); stage(2, 2);      // 12 loads in flight

#pragma unroll 4
  for (int kb = 0; kb < 124; ++kb) {
    asm volatile("s_waitcnt vmcnt(8)" ::: "memory");
    __builtin_amdgcn_s_barrier();
    stage(kb + 3, (kb + 3) & 3);
    compute(kb & 3, kb);
  }
  asm volatile("s_waitcnt vmcnt(8)" ::: "memory");
  __builtin_amdgcn_s_barrier();
  stage(127, 3);
  compute(0, 124);
  asm volatile("s_waitcnt vmcnt(8)" ::: "memory");
  __builtin_amdgcn_s_barrier();
  compute(1, 125);
  asm volatile("s_waitcnt vmcnt(4)" ::: "memory");
  __builtin_amdgcn_s_barrier();
  compute(2, 126);
  asm volatile("s_waitcnt vmcnt(0)" ::: "memory");
  __builtin_amdgcn_s_barrier();
  compute(3, 127);

  // epilogue: C/D layout col=lane&15, row=quad*4+reg
  float bias[4];
#pragma unroll
  for (int ni = 0; ni < 4; ++ni) bias[ni] = bp[wn + ni * 16 + l15];
#pragma unroll
  for (int mi = 0; mi < 4; ++mi)
#pragma unroll
    for (int ni = 0; ni < 4; ++ni)
#pragma unroll
      for (int r = 0; r < 4; ++r) {
        int t = t0 + wm + mi * 16 + quad * 4 + r;
        if (t < NTOK) {
          int n = wn + ni * 16 + l15;
          out[((size_t)b * NTOK + t) * EDIM + n] =
              floorf(acc[mi][ni][r] + bias[ni]);
        }
      }
}

// ---------------------------------------------------------------------------
extern "C" void kernel_launch(void* const* d_in, const int* in_sizes, int n_in,
                              void* d_out, int out_size, void* d_ws, size_t ws_size,
                              hipStream_t stream) {
  const float* x  = (const float*)d_in[0];
  const float* Ws = (const float*)d_in[1];
  const float* bs = (const float*)d_in[2];
  const float* Wp = (const float*)d_in[3];
  const float* bp = (const float*)d_in[4];
  float* out = (float*)d_out;

  __hip_bfloat16* enc = (__hip_bfloat16*)d_ws;   // 32 MB, phase-split layout
  __hip_bfloat16* Wt  = (__hip_bfloat16*)((char*)d_ws +
                        (size_t)BATCH * SAMPLES * EDIM * sizeof(__hip_bfloat16));

  encode_kernel<<<BATCH * (SAMPLES / 256), 256, 0, stream>>>(x, Ws, bs, enc);
  twp_kernel<<<128, 256, 0, stream>>>(Wp, Wt);
  gemm_kernel<<<BATCH * 8, 256, 0, stream>>>(enc, Wt, bp, out);
}

// Round 5
// 140.982 us; speedup vs baseline: 1.2558x; 1.2558x over previous
//
#include <hip/hip_runtime.h>
#include <hip/hip_bf16.h>
#include <cstdint>

#define BATCH   32
#define NVARS   16
#define SAMPLES 4096
#define EDIM    128
#define NTOK    1016          // (4096-32)/4
#define KDIM    4096

typedef __bf16 bf8_t __attribute__((ext_vector_type(8)));
typedef float  f4_t  __attribute__((ext_vector_type(4)));

__device__ __forceinline__ void gload_lds16(const void* g, void* l) {
  __builtin_amdgcn_global_load_lds(
      (const __attribute__((address_space(1))) unsigned int*)g,
      (__attribute__((address_space(3))) unsigned int*)l, 16, 0, 0);
}

#define WAITB(N) asm volatile("s_waitcnt vmcnt(" #N ")" ::: "memory"); \
                 __builtin_amdgcn_s_barrier();

// ---------------------------------------------------------------------------
// Stage 1: enc_p[b][phase][eblk][u(1024)][32] = floor(x@Ws+bs), bf16 (ints
// exact, truncation cast exact). Swizzle baked: phys chunk = (c+(u>>1))&3.
// v3: wave computes 16 rows of ONE plane per unit -> 1 KB contiguous stores
// (R3/R4 encode scattered 8B x 64 lanes across 16 planes - suspected ~70us).
// ---------------------------------------------------------------------------
__global__ __launch_bounds__(256) void encode_kernel(
    const float* __restrict__ x, const float* __restrict__ Ws,
    const float* __restrict__ bs, __hip_bfloat16* __restrict__ enc)
{
  __shared__ float xs[NVARS][256];
  int tid = threadIdx.x;
  int b   = blockIdx.x >> 4;
  int s0  = (blockIdx.x & 15) << 8;
  int u0  = s0 >> 2;

  {
    int col = (tid & 63) << 2;
    int v0  = tid >> 6;
#pragma unroll
    for (int j = 0; j < 4; ++j) {
      int v = v0 + j * 4;
      float4 t = *(const float4*)(x + (size_t)b * NVARS * SAMPLES
                                  + (size_t)v * SAMPLES + s0 + col);
      *(float4*)&xs[v][col] = t;
    }
  }

  int wv = tid >> 6, lane = tid & 63;
  int rlane = lane >> 2, c = lane & 3;
  int e = wv;                          // wave owns eblk e (all 4 phases)
  int d0 = e * 32 + c * 8;

  float w[NVARS][8];
#pragma unroll
  for (int v = 0; v < NVARS; ++v) {
    float4 w0 = *(const float4*)&Ws[v * EDIM + d0];
    float4 w1 = *(const float4*)&Ws[v * EDIM + d0 + 4];
    w[v][0] = w0.x; w[v][1] = w0.y; w[v][2] = w0.z; w[v][3] = w0.w;
    w[v][4] = w1.x; w[v][5] = w1.y; w[v][6] = w1.z; w[v][7] = w1.w;
  }
  float bias[8];
  {
    float4 b0 = *(const float4*)&bs[d0];
    float4 b1 = *(const float4*)&bs[d0 + 4];
    bias[0] = b0.x; bias[1] = b0.y; bias[2] = b0.z; bias[3] = b0.w;
    bias[4] = b1.x; bias[5] = b1.y; bias[6] = b1.z; bias[7] = b1.w;
  }

  __syncthreads();

#pragma unroll
  for (int p = 0; p < 4; ++p)
#pragma unroll
    for (int uc = 0; uc < 4; ++uc) {
      int ur   = uc * 16 + rlane;      // 0..63
      int sloc = 4 * ur + p;
      float acc[8];
#pragma unroll
      for (int j = 0; j < 8; ++j) acc[j] = bias[j];
#pragma unroll
      for (int v = 0; v < NVARS; ++v) {
        float xv = xs[v][sloc];
#pragma unroll
        for (int j = 0; j < 8; ++j) acc[j] += xv * w[v][j];
      }
      union { unsigned short u[8]; uint4 q; } pk;
#pragma unroll
      for (int j = 0; j < 8; ++j)
        pk.u[j] = (unsigned short)(__float_as_uint(floorf(acc[j])) >> 16);
      int u    = u0 + ur;
      int phys = (c + (u >> 1)) & 3;
      size_t off = (((size_t)b * 4 + p) * 4 + e) * 32768 + (size_t)u * 32
                 + phys * 8;
      *(uint4*)(enc + off) = pk.q;
    }
}

// ---------------------------------------------------------------------------
// W_patch [4096][128] fp32 -> Wt_p[kb(128)][n(128)][32] bf16, swizzled
// phys=(c+(n>>1))&3. NEW kb ordering: kb=(plane s)*8+delta, plane s=(phase=
// s&3, eblk=s>>2), window w=4*delta+phase -> kbase=(4d+(s&3))*128+(s>>2)*32.
// ---------------------------------------------------------------------------
__global__ __launch_bounds__(256) void twp_kernel(
    const float* __restrict__ Wp, __hip_bfloat16* __restrict__ Wt)
{
  __shared__ float ls[32][129];
  int kb    = blockIdx.x;
  int s     = kb >> 3, dlt = kb & 7;
  int kbase = (4 * dlt + (s & 3)) * 128 + (s >> 2) * 32;
#pragma unroll
  for (int r = 0; r < 16; ++r) {
    int idx = threadIdx.x + r * 256;
    ls[idx >> 7][idx & 127] = Wp[(size_t)(kbase + (idx >> 7)) * EDIM + (idx & 127)];
  }
  __syncthreads();
#pragma unroll
  for (int i = 0; i < 2; ++i) {
    int q = threadIdx.x * 2 + i;       // 0..511
    int n = q >> 2, c = q & 3;
    int p = (c + (n >> 1)) & 3;
    union { unsigned short u[8]; uint4 v; } pk;
#pragma unroll
    for (int j = 0; j < 8; ++j) {
      __hip_bfloat16 h = __float2bfloat16(ls[c * 8 + j][n]);
      pk.u[j] = *(unsigned short*)&h;
    }
    *(uint4*)(Wt + ((size_t)kb << 12) + n * 32 + p * 8) = pk.v;
  }
}

// ---------------------------------------------------------------------------
// Stage 2 GEMM: M=32512 N=128 K=4096. BM=128 BN=64, 512 blocks (2/CU),
// 4 waves, wave tile 64x32. K-loop = 16 supersteps (one (phase,eblk) plane
// each) x 8 shifts: A-plane (144 rows x 64B) loaded ONCE per superstep and
// reused for 8 k-steps at LDS offset delta -> kills the x8 window re-read
// (A traffic 1MB -> 141KB/block). B streamed via ring-4, distance-3,
// per-iter raw s_barrier + exact per-delta vmcnt gates (derived; uniform
// across waves - nA skew absorbed conservatively).
// ---------------------------------------------------------------------------
__global__ __launch_bounds__(256) void gemm_kernel(
    const __hip_bfloat16* __restrict__ enc,
    const __hip_bfloat16* __restrict__ Wt,
    const float* __restrict__ bp,
    float* __restrict__ out)
{
  __shared__ __align__(16) __hip_bfloat16 Apl[2][4608];  // 2 x 9KB (144 rows)
  __shared__ __align__(16) __hip_bfloat16 sB[4][2048];   // 4 x 4KB

  int tid  = threadIdx.x;
  int lane = tid & 63;
  int wv   = tid >> 6;
  int tm   = blockIdx.x & 7;
  int b    = (blockIdx.x >> 3) & 31;
  int nh   = blockIdx.x >> 8;
  int t0   = tm << 7;
  int n0   = nh << 6;
  int wm   = (wv >> 1) << 6;          // 0/64
  int wn   = (wv & 1) << 5;           // 0/32
  int quad = lane >> 4;
  int l15  = lane & 15;

  const __hip_bfloat16* encb = enc + (size_t)b * 524288;       // b*16*32768
  const __hip_bfloat16* bg   = Wt + n0 * 32 + wv * 512 + lane * 8;

  f4_t acc[4][2];
  f4_t zero = {0.f, 0.f, 0.f, 0.f};
#pragma unroll
  for (int i = 0; i < 4; ++i)
#pragma unroll
    for (int j = 0; j < 2; ++j) acc[i][j] = zero;

  // stage plane sp (u = t0 .. t0+143) into Apl[sp&1]; 9 units of 16 rows;
  // wave wv loads units {wv, wv+4}, wave 0 also unit 8 (nA = 3/2/2/2).
  auto stageA = [&](int sp) {
    const __hip_bfloat16* g = encb
        + (size_t)((sp & 3) * 4 + (sp >> 2)) * 32768
        + (size_t)t0 * 32 + lane * 8;
    __hip_bfloat16* dst = &Apl[sp & 1][0];
    gload_lds16(g + (size_t)(wv * 16) * 32,       dst + wv * 512);
    gload_lds16(g + (size_t)((wv + 4) * 16) * 32, dst + (wv + 4) * 512);
    if (wv == 0)
      gload_lds16(g + (size_t)(8 * 16) * 32,      dst + 8 * 512);
  };
  auto stageB = [&](int kb, int slot) {
    gload_lds16(bg + ((size_t)kb << 12), &sB[slot][wv * 512]);
  };

  int swzB = (quad + ((n0 + wn + l15) >> 1)) & 3;
  auto compute = [&](int slot, int abuf, int dlt) {
    const bf8_t* pA = (const bf8_t*)&Apl[abuf][0];
    const bf8_t* pB = (const bf8_t*)&sB[slot][0];
    int swzA = (quad + ((t0 + dlt + wm + l15) >> 1)) & 3;
    bf8_t af[4], bfr[2];
#pragma unroll
    for (int i = 0; i < 4; ++i)
      af[i] = pA[(dlt + wm + i * 16 + l15) * 4 + swzA];
#pragma unroll
    for (int j = 0; j < 2; ++j)
      bfr[j] = pB[(wn + j * 16 + l15) * 4 + swzB];
#pragma unroll
    for (int mi = 0; mi < 4; ++mi)
#pragma unroll
      for (int ni = 0; ni < 2; ++ni)
        acc[mi][ni] = __builtin_amdgcn_mfma_f32_16x16x32_bf16(
            af[mi], bfr[ni], acc[mi][ni], 0, 0, 0);
  };

  // prologue: A-plane 0, B[0..2]
  stageA(0);
  stageB(0, 0); stageB(1, 1); stageB(2, 2);

  for (int ss = 0; ss < 15; ++ss) {
    int kb = ss * 8;
    int ab = ss & 1;
    WAITB(2) stageB(kb + 3, 3);  stageA(ss + 1); compute(0, ab, 0);
    WAITB(4) stageB(kb + 4, 0);  compute(1, ab, 1);
    WAITB(4) stageB(kb + 5, 1);  compute(2, ab, 2);
    WAITB(4) stageB(kb + 6, 2);  compute(3, ab, 3);
    WAITB(2) stageB(kb + 7, 3);  compute(0, ab, 4);
    WAITB(2) stageB(kb + 8, 0);  compute(1, ab, 5);
    WAITB(2) stageB(kb + 9, 1);  compute(2, ab, 6);
    WAITB(2) stageB(kb + 10, 2); compute(3, ab, 7);
  }
  // tail superstep ss=15 (kb 120..127), plane buf 1, no A-stage
  WAITB(2) stageB(123, 3); compute(0, 1, 0);
  WAITB(2) stageB(124, 0); compute(1, 1, 1);
  WAITB(2) stageB(125, 1); compute(2, 1, 2);
  WAITB(2) stageB(126, 2); compute(3, 1, 3);
  WAITB(2) stageB(127, 3); compute(0, 1, 4);
  WAITB(2) compute(1, 1, 5);
  WAITB(1) compute(2, 1, 6);
  WAITB(0) compute(3, 1, 7);

  // epilogue: C/D layout col=lane&15, row=quad*4+reg
  float bias[2];
#pragma unroll
  for (int ni = 0; ni < 2; ++ni) bias[ni] = bp[n0 + wn + ni * 16 + l15];
#pragma unroll
  for (int mi = 0; mi < 4; ++mi)
#pragma unroll
    for (int ni = 0; ni < 2; ++ni)
#pragma unroll
      for (int r = 0; r < 4; ++r) {
        int t = t0 + wm + mi * 16 + quad * 4 + r;
        if (t < NTOK) {
          int n = n0 + wn + ni * 16 + l15;
          out[((size_t)b * NTOK + t) * EDIM + n] =
              floorf(acc[mi][ni][r] + bias[ni]);
        }
      }
}

// ---------------------------------------------------------------------------
extern "C" void kernel_launch(void* const* d_in, const int* in_sizes, int n_in,
                              void* d_out, int out_size, void* d_ws, size_t ws_size,
                              hipStream_t stream) {
  const float* x  = (const float*)d_in[0];
  const float* Ws = (const float*)d_in[1];
  const float* bs = (const float*)d_in[2];
  const float* Wp = (const float*)d_in[3];
  const float* bp = (const float*)d_in[4];
  float* out = (float*)d_out;

  __hip_bfloat16* enc = (__hip_bfloat16*)d_ws;   // 32 MB, plane-split layout
  __hip_bfloat16* Wt  = (__hip_bfloat16*)((char*)d_ws +
                        (size_t)BATCH * SAMPLES * EDIM * sizeof(__hip_bfloat16));

  encode_kernel<<<BATCH * (SAMPLES / 256), 256, 0, stream>>>(x, Ws, bs, enc);
  twp_kernel<<<128, 256, 0, stream>>>(Wp, Wt);
  gemm_kernel<<<BATCH * 8 * 2, 256, 0, stream>>>(enc, Wt, bp, out);
}